// Round 11
// baseline (183.894 us; speedup 1.0000x reference)
//
#include <hip/hip_runtime.h>

typedef unsigned short u16;
typedef unsigned int   u32;

#define BATCH  8192
#define DIM    100      // D
#define HID    110      // H
#define TSUB   19       // T = N-1 subnets
#define NSTEP  20       // N scan steps
#define KP     128      // padded K for MFMA
#define NPAD   112      // padded N (output cols) for tiles/storage
#define BN_EPS 1e-6f
#define DT_C   0.05f

#define SAB  2048                 // statsA blocks
#define SAR  (BATCH / SAB)        // 4 rows per block
#define SLICES 32                 // statsB slices (2048/32 = 64 rows per slice)
#define NBLK_SCAN 2048

typedef __bf16 v8bf __attribute__((ext_vector_type(8)));
typedef float  v4f  __attribute__((ext_vector_type(4)));
typedef float  v2f  __attribute__((ext_vector_type(2)));
typedef u16    u16x4 __attribute__((ext_vector_type(4)));

__device__ __forceinline__ u16 f2bf(float f) {
    u32 u = __float_as_uint(f);
    return (u16)((u + 0x7fffu + ((u >> 16) & 1u)) >> 16);   // RNE
}
__device__ __forceinline__ float bf2f(u16 h) {
    return __uint_as_float(((u32)h) << 16);
}
__device__ __forceinline__ void acc4(float4& s, float4& q, float4 v) {
    s.x += v.x; s.y += v.y; s.z += v.z; s.w += v.w;
    q.x += v.x * v.x; q.y += v.y * v.y; q.z += v.z * v.z; q.w += v.w * v.w;
}

// ---------------------------------------------------------------------------
// statsA: stream x coalesced once; per-block partial column sums [SAB][4200]
// and transposed bf16 activation xT[t][b][d]. 4 rows/block -> 17KB LDS,
// 8 blocks/CU schedulable, half the serial row chain of the 8-row version.
// ---------------------------------------------------------------------------
__global__ void statsA(const float* __restrict__ x, float* __restrict__ part,
                       u32* __restrict__ xT32) {
    __shared__ u16 xls[SAR][2112];
    const int tid = threadIdx.x;
    const int b0 = blockIdx.x * SAR;
    float4 s0 = {0,0,0,0}, q0 = {0,0,0,0};
    float4 s1 = {0,0,0,0}, q1 = {0,0,0,0};
    float4 s2 = {0,0,0,0}, q2 = {0,0,0,0};
#pragma unroll
    for (int r = 0; r < SAR; r++) {
        const float4* row = (const float4*)(x + (size_t)(b0 + r) * 2100);
        float4 v0 = row[tid];
        float4 v1 = row[tid + 256];
        acc4(s0, q0, v0);
        acc4(s1, q1, v1);
        u16x4 p0 = { f2bf(v0.x), f2bf(v0.y), f2bf(v0.z), f2bf(v0.w) };
        u16x4 p1 = { f2bf(v1.x), f2bf(v1.y), f2bf(v1.z), f2bf(v1.w) };
        *(u16x4*)&xls[r][tid * 4]        = p0;
        *(u16x4*)&xls[r][1024 + tid * 4] = p1;
        if (tid < 13) {
            float4 v2 = row[tid + 512];
            acc4(s2, q2, v2);
            u16x4 p2 = { f2bf(v2.x), f2bf(v2.y), f2bf(v2.z), f2bf(v2.w) };
            *(u16x4*)&xls[r][2048 + tid * 4] = p2;
        }
    }
    float* ps = part + (size_t)blockIdx.x * 4200;
    *(float4*)&ps[tid * 4]               = s0;
    *(float4*)&ps[1024 + tid * 4]        = s1;
    *(float4*)&ps[2100 + tid * 4]        = q0;
    *(float4*)&ps[2100 + 1024 + tid * 4] = q1;
    if (tid < 13) {
        *(float4*)&ps[2048 + tid * 4]        = s2;
        *(float4*)&ps[2100 + 2048 + tid * 4] = q2;
    }
    __syncthreads();
    const int TOT = TSUB * SAR * (NPAD / 2);   // 19*4*56
    for (int i = tid; i < TOT; i += 256) {
        int w = i % (NPAD / 2);
        int seg = i / (NPAD / 2);
        int r = seg % SAR, t = seg / SAR;
        int d0 = w * 2;
        u32 v = 0;
        if (d0 < DIM) {
            u16 lo = xls[r][d0 * 21 + t + 1];
            u16 hi = (d0 + 1 < DIM) ? xls[r][(d0 + 1) * 21 + t + 1] : (u16)0;
            v = (u32)lo | ((u32)hi << 16);
        }
        xT32[((size_t)t * BATCH + b0 + r) * (NPAD / 2) + w] = v;
    }
}

// statsB: out[o] = sum over SAB partial rows (SLICES slices, atomic combine)
__global__ void statsB(const float* __restrict__ part, float* __restrict__ out) {
    int gid = blockIdx.x * 256 + threadIdx.x;
    if (gid >= 4200 * SLICES) return;
    int slice = gid / 4200;
    int o = gid - slice * 4200;
    const float* p = part + (size_t)slice * (SAB / SLICES) * 4200 + o;
    float acc = 0.f;
#pragma unroll 8
    for (int i = 0; i < SAB / SLICES; i++) acc += p[(size_t)i * 4200];
    atomicAdd(&out[o], acc);
}

// ---------------------------------------------------------------------------
// wtrans: W[l][t][k][n] f32 -> WTsw[l][t][n][chunk-swizzled k] bf16.
// ---------------------------------------------------------------------------
__global__ void wtrans(const float* __restrict__ W0, const float* __restrict__ W1,
                       const float* __restrict__ W2, u16* __restrict__ WTsw) {
    __shared__ float lw[HID * HID];
    const int t = blockIdx.x, l = blockIdx.y, tid = threadIdx.x;
    const float* W; int K, N;
    if (l == 0)      { W = W0; K = DIM; N = HID; }
    else if (l == 1) { W = W1; K = HID; N = HID; }
    else             { W = W2; K = HID; N = DIM; }
    const float* Wt = W + (size_t)t * K * N;
    for (int i = tid; i < K * N; i += 256) lw[i] = Wt[i];
    __syncthreads();
    u16* out = WTsw + ((size_t)l * TSUB + t) * (NPAD * KP);
    for (int i = tid; i < NPAD * 16; i += 256) {
        int n = i / 16, p = i % 16;
        int kc = p ^ (n & 7);
        u16 o8[8];
#pragma unroll
        for (int j = 0; j < 8; j++) {
            int k = kc * 8 + j;
            float v = (k < K && n < N) ? lw[k * N + n] : 0.f;
            o8[j] = f2bf(v);
        }
        *(uint4*)&out[(size_t)n * KP + p * 8] = *(uint4*)o8;
    }
}

// ---------------------------------------------------------------------------
// GEMM v2: 512 threads (8 waves), 128-row tile, wave owns 16 rows x 112 cols.
// BMAJOR=0: Hout[t][b][NPAD]; BMAJOR=1: Hout[b][t][NPAD] (for the scan).
// ---------------------------------------------------------------------------
template <int KREAL, int NOUT, int IDXMODE, int RELU, int BMAJOR>
__global__ __launch_bounds__(512, 2)
void gemm_kernel(const u16* __restrict__ Ain,
                 const u16* __restrict__ WTswL,
                 const float* __restrict__ sumIn,
                 const float* __restrict__ sqIn,
                 const float* __restrict__ gIn,
                 const float* __restrict__ bIn,
                 u16* __restrict__ Hout,
                 float* __restrict__ sumArr,
                 float* __restrict__ sqArr) {
    __shared__ __align__(16) u16 Alds[128 * KP];   // 32 KB
    __shared__ __align__(16) u16 Blds[NPAD * KP];  // 28 KB
    __shared__ float s_sum[NPAD], s_sq[NPAD];
    __shared__ float aAffL[KP], cAffL[KP];

    const int tid = threadIdx.x;
    const int mt = blockIdx.x;
    const int t  = blockIdx.y;
    const int brow0 = mt * 128;

    if (tid < NPAD) { s_sum[tid] = 0.f; s_sq[tid] = 0.f; }
    if (tid < KREAL) {
        int idx = (IDXMODE == 0) ? (tid * 21 + (t + 1)) : (t * KREAL + tid);
        float m = sumIn[idx] * (1.f / BATCH);
        float v = sqIn[idx] * (1.f / BATCH) - m * m;
        float rstd = rsqrtf(v + BN_EPS);
        float ga = gIn[t * KREAL + tid] * rstd;
        aAffL[tid] = ga;
        cAffL[tid] = bIn[t * KREAL + tid] - m * ga;
    }

    {
        const uint4* wsrc = (const uint4*)(WTswL + (size_t)t * NPAD * KP);
        uint4* bl = (uint4*)Blds;
        for (int i = tid; i < NPAD * KP / 8; i += 512) bl[i] = wsrc[i];
    }
    const int NCH = (KREAL + 7) / 8;
    for (int i = tid; i < 128 * (16 - NCH); i += 512) {
        int row = i / (16 - NCH);
        int kc  = NCH + i % (16 - NCH);
        uint4 z = {0, 0, 0, 0};
        *(uint4*)&Alds[row * KP + (kc ^ (row & 7)) * 8] = z;
    }
    __syncthreads();

    for (int cidx = tid; cidx < 128 * NCH; cidx += 512) {
        int row = cidx / NCH;
        int kc  = cidx % NCH;
        int k0  = kc * 8;
        const u16* hrow = Ain + ((size_t)t * BATCH + brow0 + row) * NPAD + k0;
        u16 hv[8];
        *(uint4*)hv = *(const uint4*)hrow;
        u16 pk[8];
#pragma unroll
        for (int j = 0; j < 8; j++) {
            int k = k0 + j;
            float av = (k < KREAL) ? fmaf(bf2f(hv[j]), aAffL[k], cAffL[k]) : 0.f;
            if (RELU) av = fmaxf(av, 0.f);
            pk[j] = f2bf(av);
        }
        *(uint4*)&Alds[row * KP + ((kc ^ (row & 7)) * 8)] = *(uint4*)pk;
    }
    __syncthreads();

    const int lane = tid & 63;
    const int wv   = tid >> 6;            // 0..7
    const int r0   = lane & 15;
    const int q    = lane >> 4;
    const int moff = wv * 16;

    v4f acc[7];
#pragma unroll
    for (int j = 0; j < 7; j++) { v4f z = {0.f, 0.f, 0.f, 0.f}; acc[j] = z; }

#pragma unroll
    for (int ks = 0; ks < 4; ks++) {
        int cbase = ks * 4 + q;
        int row = moff + r0;
        v8bf afr = *(const v8bf*)&Alds[row * KP + ((cbase ^ (row & 7)) * 8)];
#pragma unroll
        for (int nf = 0; nf < 7; nf++) {
            int nr = nf * 16 + r0;
            v8bf bfr = *(const v8bf*)&Blds[nr * KP + ((cbase ^ (nr & 7)) * 8)];
            acc[nf] = __builtin_amdgcn_mfma_f32_16x16x32_bf16(afr, bfr, acc[nf], 0, 0, 0);
        }
    }

#pragma unroll
    for (int nf = 0; nf < 7; nf++) {
        int n = nf * 16 + r0;
#pragma unroll
        for (int rg = 0; rg < 4; rg++) {
            int grow = brow0 + moff + q * 4 + rg;
            size_t oidx = BMAJOR ? ((size_t)grow * (TSUB * NPAD) + (size_t)t * NPAD + n)
                                 : (((size_t)t * BATCH + grow) * NPAD + n);
            Hout[oidx] = f2bf(acc[nf][rg]);
        }
    }
#pragma unroll
    for (int nf = 0; nf < 7; nf++) {
        float cs = 0.f, cq = 0.f;
#pragma unroll
        for (int rg = 0; rg < 4; rg++) {
            float vv = acc[nf][rg];
            cs += vv; cq += vv * vv;
        }
        cs += __shfl_xor(cs, 16); cs += __shfl_xor(cs, 32);
        cq += __shfl_xor(cq, 16); cq += __shfl_xor(cq, 32);
        if (q == 0) {
            atomicAdd(&s_sum[nf * 16 + r0], cs);
            atomicAdd(&s_sq[nf * 16 + r0], cq);
        }
    }
    __syncthreads();
    if (tid < NOUT) {
        atomicAdd(&sumArr[t * NOUT + tid], s_sum[tid]);
        atomicAdd(&sqArr[t * NOUT + tid], s_sq[tid]);
    }
}

// ---------------------------------------------------------------------------
// finalize3: BN affine for layer 3, packed per d-PAIR as {a0,c0,a1,c1} f32x4.
// ---------------------------------------------------------------------------
__global__ void finalize3(const float* __restrict__ sum3, const float* __restrict__ sq3,
                          const float* __restrict__ g3, const float* __restrict__ b3,
                          float4* __restrict__ acg) {
    int i = blockIdx.x * 256 + threadIdx.x;      // over 19*50 d-pairs
    if (i >= TSUB * 50) return;
    int t = i / 50, p = i - t * 50;
    int e = t * DIM + 2 * p;
    float4 o;
#pragma unroll
    for (int h = 0; h < 2; h++) {
        float m = sum3[e + h] * (1.f / BATCH);
        float v = sq3[e + h] * (1.f / BATCH) - m * m;
        float rstd = rsqrtf(v + BN_EPS);
        float ga = g3[e + h] * rstd * (1.f / DIM);
        float cc = b3[e + h] * (1.f / DIM) - m * ga;
        if (h == 0) { o.x = ga; o.y = cc; } else { o.z = ga; o.w = cc; }
    }
    acg[i] = o;
}

// ---------------------------------------------------------------------------
// Scan v9 = R7/R9 structure. launch_bounds(256,4): 4 blocks/CU (50% cap),
// VGPR cap 128 — the asm block needs ~67 simultaneously-live outputs and the
// kernel peaks ~105 regs; 128 avoids spilling. NEVER tighter: spilled
// inline-asm load results get stored to scratch before vmcnt knows they
// landed (the R10 corruption).
// ---------------------------------------------------------------------------
__global__ __launch_bounds__(256, 4)
void scan_kernel(const float* __restrict__ dw,
                 const u16* __restrict__ zbuf,          // [B][T][NPAD] (b-major)
                 const float4* __restrict__ acg,        // [19][50] {a0,c0,a1,c1}
                 const float* __restrict__ z_init, const float* __restrict__ y_init,
                 float* __restrict__ yout, float* __restrict__ mred) {
    __shared__ float bsum[NSTEP];
    const int tid = threadIdx.x;
    if (tid < NSTEP) bsum[tid] = 0.f;
    __syncthreads();

    const int wv = tid >> 6, lane = tid & 63;
    const int b = blockIdx.x * 4 + wv;
    const int ll = (lane < 50) ? lane : 49;            // clamp for loads

    v4f w[10];
    u32 zr[TSUB];
    v2f zi;
    {
        const float* dwaddr = dw + (size_t)b * (DIM * NSTEP) + ll * 40;
        const u16*   zaddr  = zbuf + (size_t)b * (TSUB * NPAD) + 2 * ll;
        const float* ziaddr = z_init + 2 * ll;
        asm volatile("global_load_dwordx4 %0, %1, off offset:0"   : "=v"(w[0]) : "v"(dwaddr));
        asm volatile("global_load_dwordx4 %0, %1, off offset:16"  : "=v"(w[1]) : "v"(dwaddr));
        asm volatile("global_load_dwordx4 %0, %1, off offset:32"  : "=v"(w[2]) : "v"(dwaddr));
        asm volatile("global_load_dwordx4 %0, %1, off offset:48"  : "=v"(w[3]) : "v"(dwaddr));
        asm volatile("global_load_dwordx4 %0, %1, off offset:64"  : "=v"(w[4]) : "v"(dwaddr));
        asm volatile("global_load_dwordx4 %0, %1, off offset:80"  : "=v"(w[5]) : "v"(dwaddr));
        asm volatile("global_load_dwordx4 %0, %1, off offset:96"  : "=v"(w[6]) : "v"(dwaddr));
        asm volatile("global_load_dwordx4 %0, %1, off offset:112" : "=v"(w[7]) : "v"(dwaddr));
        asm volatile("global_load_dwordx4 %0, %1, off offset:128" : "=v"(w[8]) : "v"(dwaddr));
        asm volatile("global_load_dwordx4 %0, %1, off offset:144" : "=v"(w[9]) : "v"(dwaddr));
#pragma unroll
        for (int t = 0; t < TSUB; t++)
            asm volatile("global_load_dword %0, %1, off offset:%2"
                         : "=v"(zr[t]) : "v"(zaddr), "i"(t * NPAD * 2));
        asm volatile("global_load_dwordx2 %0, %1, off" : "=v"(zi) : "v"(ziaddr));
        asm volatile("s_waitcnt vmcnt(0)" ::: "memory");
        __builtin_amdgcn_sched_barrier(0);
    }

    float acc[NSTEP];
#pragma unroll
    for (int k = 0; k < NSTEP; k++) acc[k] = 0.f;
    if (lane < 50) {
        acc[0] = zi[0] * w[0][0] + zi[1] * w[5][0];
#pragma unroll
        for (int t = 0; t < TSUB; t++) {
            float4 ac = acg[t * 50 + ll];
            u32 z = zr[t];
            float za0 = fmaf(bf2f((u16)(z & 0xffffu)), ac.x, ac.y);
            float za1 = fmaf(bf2f((u16)(z >> 16)),     ac.z, ac.w);
            const int n = t + 1, j = n >> 2, k = n & 3;   // compile-time per unrolled t
            acc[n] += w[j][k] * za0 + w[5 + j][k] * za1;
        }
    }

#pragma unroll
    for (int m = 1; m < 64; m <<= 1) {
#pragma unroll
        for (int k = 0; k < NSTEP; k++) acc[k] += __shfl_xor(acc[k], m, 64);
    }

    const float yi = y_init[0];
    float y = yi, ysave = 0.f;
#pragma unroll
    for (int i = 0; i < NSTEP; i++) {
        y = y - DT_C * __sinf(y) + acc[i];
        if (i == lane - 1) ysave = y;                  // lane n holds y_n
    }
    if (lane == 0) yout[b] = y;                        // y_final = y_20
    if (lane >= 1 && lane < NSTEP) atomicAdd(&bsum[lane], ysave);
    __syncthreads();
    if (tid >= 1 && tid < NSTEP) mred[blockIdx.x * NSTEP + tid] = bsum[tid];
}

// ---------------------------------------------------------------------------
// meanred: meanout[n] = mean over batch of y_n (block n sums 2048 partials).
// ---------------------------------------------------------------------------
__global__ void meanred(const float* __restrict__ mred, const float* __restrict__ y_init,
                        float* __restrict__ meanout) {
    const int n = blockIdx.x, tid = threadIdx.x;
    if (n == 0) { if (tid == 0) meanout[0] = y_init[0]; return; }
    float s = 0.f;
    for (int i = tid; i < NBLK_SCAN; i += 256) s += mred[(size_t)i * NSTEP + n];
#pragma unroll
    for (int m = 1; m < 64; m <<= 1) s += __shfl_xor(s, m, 64);
    __shared__ float ws4[4];
    if ((tid & 63) == 0) ws4[tid >> 6] = s;
    __syncthreads();
    if (tid == 0) meanout[n] = (ws4[0] + ws4[1] + ws4[2] + ws4[3]) * (1.f / BATCH);
}

// ---------------------------------------------------------------------------
extern "C" void kernel_launch(void* const* d_in, const int* in_sizes, int n_in,
                              void* d_out, int out_size, void* d_ws, size_t ws_size,
                              hipStream_t stream) {
    const float* dw     = (const float*)d_in[0];
    const float* x      = (const float*)d_in[1];
    const float* y_init = (const float*)d_in[3];
    const float* z_init = (const float*)d_in[4];
    const float* g0 = (const float*)d_in[5];
    const float* b0 = (const float*)d_in[6];
    const float* W0 = (const float*)d_in[7];
    const float* g1 = (const float*)d_in[8];
    const float* b1 = (const float*)d_in[9];
    const float* W1 = (const float*)d_in[10];
    const float* g2 = (const float*)d_in[11];
    const float* b2 = (const float*)d_in[12];
    const float* W2 = (const float*)d_in[13];
    // d_in[14] = bias2: cancelled by the following BatchNorm -> unused
    const float* g3 = (const float*)d_in[15];
    const float* b3 = (const float*)d_in[16];

    char* ws = (char*)d_ws;
    size_t off = 0;
    auto alloc = [&](size_t bytes) -> void* {
        off = (off + 255) & ~(size_t)255;
        void* p = ws + off;
        off += bytes;
        return p;
    };

    const int nStats = 4200 + TSUB * HID * 2 * 2 + TSUB * DIM * 2;
    float* statsBlk = (float*)alloc((size_t)nStats * 4);
    float* sum0 = statsBlk;            float* sq0  = sum0 + 2100;
    float* sum1 = sum0 + 4200;         float* sq1  = sum1 + TSUB * HID;
    float* sum2 = sq1 + TSUB * HID;    float* sq2  = sum2 + TSUB * HID;
    float* sum3 = sq2 + TSUB * HID;    float* sq3  = sum3 + TSUB * DIM;

    u16* WTsw = (u16*)alloc((size_t)3 * TSUB * NPAD * KP * 2);
    float4* acg = (float4*)alloc((size_t)TSUB * 50 * 16);           // 15.2 KB
    float* mred = (float*)alloc((size_t)NBLK_SCAN * NSTEP * 4);     // 160 KB

    const size_t hBytes = (size_t)TSUB * BATCH * NPAD * 2;          // 34.9 MB
    u16* h0 = (u16*)alloc(hBytes);
    u16* h1 = (u16*)alloc(hBytes);
    u16* outbuf = h0;                 // b-major [B][T][NPAD]; h0 dead after gemm1
    float* part = (float*)h0;         // stats partials alias h0 (34.4 MB <= 34.9)
    u32*  xT32  = (u32*)h1;           // xT aliases h1

    float* yout = (float*)d_out;
    float* meanout = yout + BATCH;

    hipMemsetAsync(statsBlk, 0, (size_t)nStats * 4, stream);

    wtrans<<<dim3(TSUB, 3), 256, 0, stream>>>(W0, W1, W2, WTsw);
    statsA<<<SAB, 256, 0, stream>>>(x, part, xT32);
    statsB<<<(4200 * SLICES + 255) / 256, 256, 0, stream>>>(part, sum0);

    const u16* xT = (const u16*)xT32;
    u16* WT0 = WTsw;
    u16* WT1 = WTsw + (size_t)TSUB * NPAD * KP;
    u16* WT2 = WTsw + (size_t)2 * TSUB * NPAD * KP;

    gemm_kernel<DIM, HID, 0, 0, 0><<<dim3(64, TSUB), 512, 0, stream>>>(xT, WT0, sum0, sq0, g0, b0, h0, sum1, sq1);
    gemm_kernel<HID, HID, 1, 1, 0><<<dim3(64, TSUB), 512, 0, stream>>>(h0, WT1, sum1, sq1, g1, b1, h1, sum2, sq2);
    gemm_kernel<HID, DIM, 1, 1, 1><<<dim3(64, TSUB), 512, 0, stream>>>(h1, WT2, sum2, sq2, g2, b2, outbuf, sum3, sq3);

    finalize3<<<4, 256, 0, stream>>>(sum3, sq3, g3, b3, acg);
    scan_kernel<<<NBLK_SCAN, 256, 0, stream>>>(dw, outbuf, acg, z_init, y_init, yout, mred);
    meanred<<<NSTEP, 256, 0, stream>>>(mred, y_init, meanout);
}

// Round 12
// 166.356 us; speedup vs baseline: 1.1054x; 1.1054x over previous
//
#include <hip/hip_runtime.h>

typedef unsigned short u16;
typedef unsigned int   u32;

#define BATCH  8192
#define DIM    100      // D
#define HID    110      // H
#define TSUB   19       // T = N-1 subnets
#define NSTEP  20       // N scan steps
#define KP     128      // padded K for MFMA
#define NPAD   112      // padded N (output cols) for tiles/storage
#define BN_EPS 1e-6f
#define DT_C   0.05f

#define SAB  2048                 // statsA blocks
#define SAR  (BATCH / SAB)        // 4 rows per block
#define SLICES 32                 // statsB slices
#define NBLK_SCAN 2048

typedef __bf16 v8bf __attribute__((ext_vector_type(8)));
typedef float  v4f  __attribute__((ext_vector_type(4)));
typedef float  v2f  __attribute__((ext_vector_type(2)));
typedef u16    u16x4 __attribute__((ext_vector_type(4)));

__device__ __forceinline__ u16 f2bf(float f) {
    u32 u = __float_as_uint(f);
    return (u16)((u + 0x7fffu + ((u >> 16) & 1u)) >> 16);   // RNE
}
__device__ __forceinline__ float bf2f(u16 h) {
    return __uint_as_float(((u32)h) << 16);
}
__device__ __forceinline__ void acc4(float4& s, float4& q, float4 v) {
    s.x += v.x; s.y += v.y; s.z += v.z; s.w += v.w;
    q.x += v.x * v.x; q.y += v.y * v.y; q.z += v.z * v.z; q.w += v.w * v.w;
}

// ---------------------------------------------------------------------------
// statsA: stream x coalesced once; per-block partial column sums [SAB][4200]
// and transposed bf16 activation xT[t][b][d].
// ---------------------------------------------------------------------------
__global__ void statsA(const float* __restrict__ x, float* __restrict__ part,
                       u32* __restrict__ xT32) {
    __shared__ u16 xls[SAR][2112];
    const int tid = threadIdx.x;
    const int b0 = blockIdx.x * SAR;
    float4 s0 = {0,0,0,0}, q0 = {0,0,0,0};
    float4 s1 = {0,0,0,0}, q1 = {0,0,0,0};
    float4 s2 = {0,0,0,0}, q2 = {0,0,0,0};
#pragma unroll
    for (int r = 0; r < SAR; r++) {
        const float4* row = (const float4*)(x + (size_t)(b0 + r) * 2100);
        float4 v0 = row[tid];
        float4 v1 = row[tid + 256];
        acc4(s0, q0, v0);
        acc4(s1, q1, v1);
        u16x4 p0 = { f2bf(v0.x), f2bf(v0.y), f2bf(v0.z), f2bf(v0.w) };
        u16x4 p1 = { f2bf(v1.x), f2bf(v1.y), f2bf(v1.z), f2bf(v1.w) };
        *(u16x4*)&xls[r][tid * 4]        = p0;
        *(u16x4*)&xls[r][1024 + tid * 4] = p1;
        if (tid < 13) {
            float4 v2 = row[tid + 512];
            acc4(s2, q2, v2);
            u16x4 p2 = { f2bf(v2.x), f2bf(v2.y), f2bf(v2.z), f2bf(v2.w) };
            *(u16x4*)&xls[r][2048 + tid * 4] = p2;
        }
    }
    float* ps = part + (size_t)blockIdx.x * 4200;
    *(float4*)&ps[tid * 4]               = s0;
    *(float4*)&ps[1024 + tid * 4]        = s1;
    *(float4*)&ps[2100 + tid * 4]        = q0;
    *(float4*)&ps[2100 + 1024 + tid * 4] = q1;
    if (tid < 13) {
        *(float4*)&ps[2048 + tid * 4]        = s2;
        *(float4*)&ps[2100 + 2048 + tid * 4] = q2;
    }
    __syncthreads();
    const int TOT = TSUB * SAR * (NPAD / 2);   // 19*4*56
    for (int i = tid; i < TOT; i += 256) {
        int w = i % (NPAD / 2);
        int seg = i / (NPAD / 2);
        int r = seg % SAR, t = seg / SAR;
        int d0 = w * 2;
        u32 v = 0;
        if (d0 < DIM) {
            u16 lo = xls[r][d0 * 21 + t + 1];
            u16 hi = (d0 + 1 < DIM) ? xls[r][(d0 + 1) * 21 + t + 1] : (u16)0;
            v = (u32)lo | ((u32)hi << 16);
        }
        xT32[((size_t)t * BATCH + b0 + r) * (NPAD / 2) + w] = v;
    }
}

// statsB: out[o] = sum over SAB partial rows (SLICES slices, atomic combine)
__global__ void statsB(const float* __restrict__ part, float* __restrict__ out) {
    int gid = blockIdx.x * 256 + threadIdx.x;
    if (gid >= 4200 * SLICES) return;
    int slice = gid / 4200;
    int o = gid - slice * 4200;
    const float* p = part + (size_t)slice * (SAB / SLICES) * 4200 + o;
    float acc = 0.f;
#pragma unroll 8
    for (int i = 0; i < SAB / SLICES; i++) acc += p[(size_t)i * 4200];
    atomicAdd(&out[o], acc);
}

// ---------------------------------------------------------------------------
// wtrans: W[l][t][k][n] f32 -> WTsw[l][t][n][chunk-swizzled k] bf16.
// ---------------------------------------------------------------------------
__global__ void wtrans(const float* __restrict__ W0, const float* __restrict__ W1,
                       const float* __restrict__ W2, u16* __restrict__ WTsw) {
    __shared__ float lw[HID * HID];
    const int t = blockIdx.x, l = blockIdx.y, tid = threadIdx.x;
    const float* W; int K, N;
    if (l == 0)      { W = W0; K = DIM; N = HID; }
    else if (l == 1) { W = W1; K = HID; N = HID; }
    else             { W = W2; K = HID; N = DIM; }
    const float* Wt = W + (size_t)t * K * N;
    for (int i = tid; i < K * N; i += 256) lw[i] = Wt[i];
    __syncthreads();
    u16* out = WTsw + ((size_t)l * TSUB + t) * (NPAD * KP);
    for (int i = tid; i < NPAD * 16; i += 256) {
        int n = i / 16, p = i % 16;
        int kc = p ^ (n & 7);
        u16 o8[8];
#pragma unroll
        for (int j = 0; j < 8; j++) {
            int k = kc * 8 + j;
            float v = (k < K && n < N) ? lw[k * N + n] : 0.f;
            o8[j] = f2bf(v);
        }
        *(uint4*)&out[(size_t)n * KP + p * 8] = *(uint4*)o8;
    }
}

// ---------------------------------------------------------------------------
// scaleW0: fold the layer-0 BN scale a0 into WT0 in place (W0' = diag(a0)W0).
// The BN offset c0 is dropped: it shifts h0 columns by a constant, which the
// next BatchNorm (shift-invariant, stats computed on the same shifted values)
// cancels exactly. WT0 is rewritten by wtrans every launch -> replay-safe.
// ---------------------------------------------------------------------------
__global__ void scaleW0(const float* __restrict__ sum0, const float* __restrict__ sq0,
                        const float* __restrict__ g0, u16* __restrict__ WT0) {
    __shared__ float aL[DIM];
    const int t = blockIdx.x, tid = threadIdx.x;
    if (tid < DIM) {
        int idx = tid * 21 + (t + 1);
        float m = sum0[idx] * (1.f / BATCH);
        float v = sq0[idx] * (1.f / BATCH) - m * m;
        aL[tid] = g0[t * DIM + tid] * rsqrtf(v + BN_EPS);
    }
    __syncthreads();
    u16* wt = WT0 + (size_t)t * NPAD * KP;
    for (int i = tid; i < NPAD * 16; i += 256) {
        int n = i >> 4, p = i & 15;
        int kc = p ^ (n & 7);
        uint4 v4 = *(uint4*)&wt[(size_t)n * KP + p * 8];
        u16* e = (u16*)&v4;
#pragma unroll
        for (int j = 0; j < 8; j++) {
            int k = kc * 8 + j;
            if (k < DIM) e[j] = f2bf(bf2f(e[j]) * aL[k]);
        }
        *(uint4*)&wt[(size_t)n * KP + p * 8] = v4;
    }
}

// ---------------------------------------------------------------------------
// GEMM v3: A-path direct global->registers (no A-LDS, no 2nd barrier).
// Lane (r0,q) of wave wv owns row wv*16+r0; its 4 uint4 loads cover K=128 and
// are dense across the wave (16 rows x 64B = 16 lines / 1KB per instr).
// AFFINE=0 (gemm0): A used raw (scale pre-folded into W by scaleW0).
// AFFINE=1: in-register a*h+c [+relu]; k >= KREAL has a=c=0 -> frag 0.
// Chunks 14,15 (k>=112) are address-clamped; their B rows are zero.
// 512 threads, launch_bounds(512,4) -> 2 blocks/CU (16 waves, 50%).
// ---------------------------------------------------------------------------
template <int KREAL, int NOUT, int AFFINE, int RELU, int BMAJOR>
__global__ __launch_bounds__(512, 4)
void gemm_kernel(const u16* __restrict__ Ain,
                 const u16* __restrict__ WTswL,
                 const float* __restrict__ sumIn,
                 const float* __restrict__ sqIn,
                 const float* __restrict__ gIn,
                 const float* __restrict__ bIn,
                 u16* __restrict__ Hout,
                 float* __restrict__ sumArr,
                 float* __restrict__ sqArr) {
    __shared__ __align__(16) u16 Blds[NPAD * KP];  // 28 KB
    __shared__ float s_sum[NPAD], s_sq[NPAD];
    __shared__ float aAffL[KP], cAffL[KP];

    const int tid = threadIdx.x;
    const int mt = blockIdx.x;
    const int t  = blockIdx.y;
    const int brow0 = mt * 128;

    if (tid < NPAD) { s_sum[tid] = 0.f; s_sq[tid] = 0.f; }
    if (AFFINE) {
        if (tid >= KREAL && tid < KP) { aAffL[tid] = 0.f; cAffL[tid] = 0.f; }
        if (tid < KREAL) {
            int idx = t * KREAL + tid;
            float m = sumIn[idx] * (1.f / BATCH);
            float v = sqIn[idx] * (1.f / BATCH) - m * m;
            float rstd = rsqrtf(v + BN_EPS);
            float ga = gIn[idx] * rstd;
            aAffL[tid] = ga;
            cAffL[tid] = bIn[idx] - m * ga;
        }
    }

    // stage B (pre-swizzled plane, straight copy)
    {
        const uint4* wsrc = (const uint4*)(WTswL + (size_t)t * NPAD * KP);
        uint4* bl = (uint4*)Blds;
        for (int i = tid; i < NPAD * KP / 8; i += 512) bl[i] = wsrc[i];
    }
    __syncthreads();

    const int lane = tid & 63;
    const int wv   = tid >> 6;            // 0..7
    const int r0   = lane & 15;
    const int q    = lane >> 4;
    const int row  = wv * 16 + r0;        // 0..127

    // ---- A direct: 4 uint4 loads cover the lane's full K ----
    const u16* arow = Ain + ((size_t)t * BATCH + brow0 + row) * NPAD;
    u16 hv[4][8];
#pragma unroll
    for (int ks = 0; ks < 4; ks++) {
        int cb = ks * 4 + q;
        int cbl = (cb > 13) ? 13 : cb;    // clamp: k>=112 rows of B are zero
        *(uint4*)hv[ks] = *(const uint4*)(arow + cbl * 8);
    }
    v8bf afr[4];
#pragma unroll
    for (int ks = 0; ks < 4; ks++) {
        if (AFFINE) {
            int cb = ks * 4 + q;          // real chunk: k>=KREAL has a=c=0
            const float* ap = &aAffL[cb * 8];
            const float* cp = &cAffL[cb * 8];
            u16 pk[8];
#pragma unroll
            for (int j = 0; j < 8; j++) {
                float av = fmaf(bf2f(hv[ks][j]), ap[j], cp[j]);
                if (RELU) av = fmaxf(av, 0.f);
                pk[j] = f2bf(av);
            }
            afr[ks] = *(v8bf*)pk;
        } else {
            afr[ks] = *(v8bf*)hv[ks];
        }
    }

    // ---- MFMA: wave owns 16 rows x 112 cols ----
    v4f acc[7];
#pragma unroll
    for (int j = 0; j < 7; j++) { v4f z = {0.f, 0.f, 0.f, 0.f}; acc[j] = z; }
#pragma unroll
    for (int ks = 0; ks < 4; ks++) {
        int cbase = ks * 4 + q;
#pragma unroll
        for (int nf = 0; nf < 7; nf++) {
            int nr = nf * 16 + r0;
            v8bf bfr = *(const v8bf*)&Blds[nr * KP + ((cbase ^ (nr & 7)) * 8)];
            acc[nf] = __builtin_amdgcn_mfma_f32_16x16x32_bf16(afr[ks], bfr, acc[nf], 0, 0, 0);
        }
    }

    // ---- epilogue: store bf16 pre-BN values + column stats ----
#pragma unroll
    for (int nf = 0; nf < 7; nf++) {
        int n = nf * 16 + r0;
#pragma unroll
        for (int rg = 0; rg < 4; rg++) {
            int grow = brow0 + wv * 16 + q * 4 + rg;
            size_t oidx = BMAJOR ? ((size_t)grow * (TSUB * NPAD) + (size_t)t * NPAD + n)
                                 : (((size_t)t * BATCH + grow) * NPAD + n);
            Hout[oidx] = f2bf(acc[nf][rg]);
        }
    }
#pragma unroll
    for (int nf = 0; nf < 7; nf++) {
        float cs = 0.f, cq = 0.f;
#pragma unroll
        for (int rg = 0; rg < 4; rg++) {
            float vv = acc[nf][rg];
            cs += vv; cq += vv * vv;
        }
        cs += __shfl_xor(cs, 16); cs += __shfl_xor(cs, 32);
        cq += __shfl_xor(cq, 16); cq += __shfl_xor(cq, 32);
        if (q == 0) {
            atomicAdd(&s_sum[nf * 16 + r0], cs);
            atomicAdd(&s_sq[nf * 16 + r0], cq);
        }
    }
    __syncthreads();
    if (tid < NOUT) {
        atomicAdd(&sumArr[t * NOUT + tid], s_sum[tid]);
        atomicAdd(&sqArr[t * NOUT + tid], s_sq[tid]);
    }
}

// ---------------------------------------------------------------------------
// finalize3: BN affine for layer 3, packed per d-PAIR as {a0,c0,a1,c1} f32x4.
// ---------------------------------------------------------------------------
__global__ void finalize3(const float* __restrict__ sum3, const float* __restrict__ sq3,
                          const float* __restrict__ g3, const float* __restrict__ b3,
                          float4* __restrict__ acg) {
    int i = blockIdx.x * 256 + threadIdx.x;      // over 19*50 d-pairs
    if (i >= TSUB * 50) return;
    int t = i / 50, p = i - t * 50;
    int e = t * DIM + 2 * p;
    float4 o;
#pragma unroll
    for (int h = 0; h < 2; h++) {
        float m = sum3[e + h] * (1.f / BATCH);
        float v = sq3[e + h] * (1.f / BATCH) - m * m;
        float rstd = rsqrtf(v + BN_EPS);
        float ga = g3[e + h] * rstd * (1.f / DIM);
        float cc = b3[e + h] * (1.f / DIM) - m * ga;
        if (h == 0) { o.x = ga; o.y = cc; } else { o.z = ga; o.w = cc; }
    }
    acg[i] = o;
}

// ---------------------------------------------------------------------------
// Scan (R7/R9 structure; launch_bounds(256,4) -> VGPR cap 128, no asm spills).
// ---------------------------------------------------------------------------
__global__ __launch_bounds__(256, 4)
void scan_kernel(const float* __restrict__ dw,
                 const u16* __restrict__ zbuf,          // [B][T][NPAD] (b-major)
                 const float4* __restrict__ acg,        // [19][50] {a0,c0,a1,c1}
                 const float* __restrict__ z_init, const float* __restrict__ y_init,
                 float* __restrict__ yout, float* __restrict__ mred) {
    __shared__ float bsum[NSTEP];
    const int tid = threadIdx.x;
    if (tid < NSTEP) bsum[tid] = 0.f;
    __syncthreads();

    const int wv = tid >> 6, lane = tid & 63;
    const int b = blockIdx.x * 4 + wv;
    const int ll = (lane < 50) ? lane : 49;            // clamp for loads

    v4f w[10];
    u32 zr[TSUB];
    v2f zi;
    {
        const float* dwaddr = dw + (size_t)b * (DIM * NSTEP) + ll * 40;
        const u16*   zaddr  = zbuf + (size_t)b * (TSUB * NPAD) + 2 * ll;
        const float* ziaddr = z_init + 2 * ll;
        asm volatile("global_load_dwordx4 %0, %1, off offset:0"   : "=v"(w[0]) : "v"(dwaddr));
        asm volatile("global_load_dwordx4 %0, %1, off offset:16"  : "=v"(w[1]) : "v"(dwaddr));
        asm volatile("global_load_dwordx4 %0, %1, off offset:32"  : "=v"(w[2]) : "v"(dwaddr));
        asm volatile("global_load_dwordx4 %0, %1, off offset:48"  : "=v"(w[3]) : "v"(dwaddr));
        asm volatile("global_load_dwordx4 %0, %1, off offset:64"  : "=v"(w[4]) : "v"(dwaddr));
        asm volatile("global_load_dwordx4 %0, %1, off offset:80"  : "=v"(w[5]) : "v"(dwaddr));
        asm volatile("global_load_dwordx4 %0, %1, off offset:96"  : "=v"(w[6]) : "v"(dwaddr));
        asm volatile("global_load_dwordx4 %0, %1, off offset:112" : "=v"(w[7]) : "v"(dwaddr));
        asm volatile("global_load_dwordx4 %0, %1, off offset:128" : "=v"(w[8]) : "v"(dwaddr));
        asm volatile("global_load_dwordx4 %0, %1, off offset:144" : "=v"(w[9]) : "v"(dwaddr));
#pragma unroll
        for (int t = 0; t < TSUB; t++)
            asm volatile("global_load_dword %0, %1, off offset:%2"
                         : "=v"(zr[t]) : "v"(zaddr), "i"(t * NPAD * 2));
        asm volatile("global_load_dwordx2 %0, %1, off" : "=v"(zi) : "v"(ziaddr));
        asm volatile("s_waitcnt vmcnt(0)" ::: "memory");
        __builtin_amdgcn_sched_barrier(0);
    }

    float acc[NSTEP];
#pragma unroll
    for (int k = 0; k < NSTEP; k++) acc[k] = 0.f;
    if (lane < 50) {
        acc[0] = zi[0] * w[0][0] + zi[1] * w[5][0];
#pragma unroll
        for (int t = 0; t < TSUB; t++) {
            float4 ac = acg[t * 50 + ll];
            u32 z = zr[t];
            float za0 = fmaf(bf2f((u16)(z & 0xffffu)), ac.x, ac.y);
            float za1 = fmaf(bf2f((u16)(z >> 16)),     ac.z, ac.w);
            const int n = t + 1, j = n >> 2, k = n & 3;   // compile-time per unrolled t
            acc[n] += w[j][k] * za0 + w[5 + j][k] * za1;
        }
    }

#pragma unroll
    for (int m = 1; m < 64; m <<= 1) {
#pragma unroll
        for (int k = 0; k < NSTEP; k++) acc[k] += __shfl_xor(acc[k], m, 64);
    }

    const float yi = y_init[0];
    float y = yi, ysave = 0.f;
#pragma unroll
    for (int i = 0; i < NSTEP; i++) {
        y = y - DT_C * __sinf(y) + acc[i];
        if (i == lane - 1) ysave = y;                  // lane n holds y_n
    }
    if (lane == 0) yout[b] = y;                        // y_final = y_20
    if (lane >= 1 && lane < NSTEP) atomicAdd(&bsum[lane], ysave);
    __syncthreads();
    if (tid >= 1 && tid < NSTEP) mred[blockIdx.x * NSTEP + tid] = bsum[tid];
}

// ---------------------------------------------------------------------------
// meanred: meanout[n] = mean over batch of y_n (block n sums 2048 partials).
// ---------------------------------------------------------------------------
__global__ void meanred(const float* __restrict__ mred, const float* __restrict__ y_init,
                        float* __restrict__ meanout) {
    const int n = blockIdx.x, tid = threadIdx.x;
    if (n == 0) { if (tid == 0) meanout[0] = y_init[0]; return; }
    float s = 0.f;
    for (int i = tid; i < NBLK_SCAN; i += 256) s += mred[(size_t)i * NSTEP + n];
#pragma unroll
    for (int m = 1; m < 64; m <<= 1) s += __shfl_xor(s, m, 64);
    __shared__ float ws4[4];
    if ((tid & 63) == 0) ws4[tid >> 6] = s;
    __syncthreads();
    if (tid == 0) meanout[n] = (ws4[0] + ws4[1] + ws4[2] + ws4[3]) * (1.f / BATCH);
}

// ---------------------------------------------------------------------------
extern "C" void kernel_launch(void* const* d_in, const int* in_sizes, int n_in,
                              void* d_out, int out_size, void* d_ws, size_t ws_size,
                              hipStream_t stream) {
    const float* dw     = (const float*)d_in[0];
    const float* x      = (const float*)d_in[1];
    const float* y_init = (const float*)d_in[3];
    const float* z_init = (const float*)d_in[4];
    const float* g0 = (const float*)d_in[5];
    const float* b0 = (const float*)d_in[6];
    const float* W0 = (const float*)d_in[7];
    const float* g1 = (const float*)d_in[8];
    const float* b1 = (const float*)d_in[9];
    const float* W1 = (const float*)d_in[10];
    const float* g2 = (const float*)d_in[11];
    const float* b2 = (const float*)d_in[12];
    const float* W2 = (const float*)d_in[13];
    // d_in[14] = bias2: cancelled by the following BatchNorm -> unused
    const float* g3 = (const float*)d_in[15];
    const float* b3 = (const float*)d_in[16];

    char* ws = (char*)d_ws;
    size_t off = 0;
    auto alloc = [&](size_t bytes) -> void* {
        off = (off + 255) & ~(size_t)255;
        void* p = ws + off;
        off += bytes;
        return p;
    };

    const int nStats = 4200 + TSUB * HID * 2 * 2 + TSUB * DIM * 2;
    float* statsBlk = (float*)alloc((size_t)nStats * 4);
    float* sum0 = statsBlk;            float* sq0  = sum0 + 2100;
    float* sum1 = sum0 + 4200;         float* sq1  = sum1 + TSUB * HID;
    float* sum2 = sq1 + TSUB * HID;    float* sq2  = sum2 + TSUB * HID;
    float* sum3 = sq2 + TSUB * HID;    float* sq3  = sum3 + TSUB * DIM;

    u16* WTsw = (u16*)alloc((size_t)3 * TSUB * NPAD * KP * 2);
    float4* acg = (float4*)alloc((size_t)TSUB * 50 * 16);           // 15.2 KB
    float* mred = (float*)alloc((size_t)NBLK_SCAN * NSTEP * 4);     // 160 KB

    const size_t hBytes = (size_t)TSUB * BATCH * NPAD * 2;          // 34.9 MB
    u16* h0 = (u16*)alloc(hBytes);
    u16* h1 = (u16*)alloc(hBytes);
    u16* outbuf = h0;                 // b-major [B][T][NPAD]; h0 dead after gemm1
    float* part = (float*)h0;         // stats partials alias h0 (34.4 MB <= 34.9)
    u32*  xT32  = (u32*)h1;           // xT aliases h1

    float* yout = (float*)d_out;
    float* meanout = yout + BATCH;

    hipMemsetAsync(statsBlk, 0, (size_t)nStats * 4, stream);

    wtrans<<<dim3(TSUB, 3), 256, 0, stream>>>(W0, W1, W2, WTsw);
    statsA<<<SAB, 256, 0, stream>>>(x, part, xT32);
    statsB<<<(4200 * SLICES + 255) / 256, 256, 0, stream>>>(part, sum0);

    const u16* xT = (const u16*)xT32;
    u16* WT0 = WTsw;
    u16* WT1 = WTsw + (size_t)TSUB * NPAD * KP;
    u16* WT2 = WTsw + (size_t)2 * TSUB * NPAD * KP;

    scaleW0<<<TSUB, 256, 0, stream>>>(sum0, sq0, g0, WT0);

    gemm_kernel<DIM, HID, 0, 0, 0><<<dim3(64, TSUB), 512, 0, stream>>>(xT, WT0, sum0, sq0, g0, b0, h0, sum1, sq1);
    gemm_kernel<HID, HID, 1, 1, 0><<<dim3(64, TSUB), 512, 0, stream>>>(h0, WT1, sum1, sq1, g1, b1, h1, sum2, sq2);
    gemm_kernel<HID, DIM, 1, 1, 1><<<dim3(64, TSUB), 512, 0, stream>>>(h1, WT2, sum2, sq2, g2, b2, outbuf, sum3, sq3);

    finalize3<<<4, 256, 0, stream>>>(sum3, sq3, g3, b3, acg);
    scan_kernel<<<NBLK_SCAN, 256, 0, stream>>>(dw, outbuf, acg, z_init, y_init, yout, mred);
    meanred<<<NSTEP, 256, 0, stream>>>(mred, y_init, meanout);
}